// Round 18
// baseline (179.318 us; speedup 1.0000x reference)
//
#include <hip/hip_runtime.h>
#include <hip/hip_fp16.h>

#define T_SEQ 2048
#define D_MODEL 1024
#define NB 2
#define NH 16
#define HD 64
#define NZ 5

using f16x8 = __attribute__((ext_vector_type(8))) _Float16;
using f16x4 = __attribute__((ext_vector_type(4))) _Float16;
using f32x4 = __attribute__((ext_vector_type(4))) float;
using i32x4 = __attribute__((ext_vector_type(4))) int;

// amax slots padded to 128 B (32 uints) apart: one cache line per slot
#define ASLOT 32

__device__ __forceinline__ float fexp2(float x) { return __builtin_amdgcn_exp2f(x); }

__device__ __forceinline__ void gload_lds16(const void* g, void* l) {
    __builtin_amdgcn_global_load_lds((const __attribute__((address_space(1))) void*)g,
                                     (__attribute__((address_space(3))) void*)l, 16, 0, 0);
}

// ---------- absmax: y<4 -> x slice y (slot 0); y>=4 -> W[y-4] (slot 1+y-4) ----------
__global__ __launch_bounds__(256)
void k_absmax8(const float* __restrict__ x,
               const float* __restrict__ w0, const float* __restrict__ w1,
               const float* __restrict__ w2, const float* __restrict__ w3,
               unsigned int* __restrict__ amax) {
    __shared__ float wred[4];
    const int y = blockIdx.y;
    const float* p; int slot;
    if (y < 4) { p = x + (long)y * 1048576; slot = 0; }
    else { int w = y - 4; p = (w == 0) ? w0 : (w == 1) ? w1 : (w == 2) ? w2 : w3; slot = 1 + w; }
    const float4* p4 = (const float4*)p;
    const long i0 = (long)blockIdx.x * 256 + threadIdx.x;   // 0..8191
    float m = 0.f;
    #pragma unroll 4
    for (int it = 0; it < 32; ++it) {                       // 32*8192 = 262144 float4
        float4 v = p4[i0 + (long)it * 8192];
        m = fmaxf(fmaxf(fmaxf(fabsf(v.x), fabsf(v.y)), fmaxf(fabsf(v.z), fabsf(v.w))), m);
    }
    #pragma unroll
    for (int off = 1; off < 64; off <<= 1) m = fmaxf(m, __shfl_xor(m, off));
    if ((threadIdx.x & 63) == 0) wred[threadIdx.x >> 6] = m;
    __syncthreads();
    if (threadIdx.x == 0) {
        float mm = fmaxf(fmaxf(wred[0], wred[1]), fmaxf(wred[2], wred[3]));
        if (mm > 0.f) atomicMax(amax + slot * ASLOT, __float_as_uint(mm));
    }
}

__device__ __forceinline__ unsigned int quant_pack4i(float4 v, float inv) {
    int q0 = (int)fminf(127.f, fmaxf(-128.f, rintf(v.x * inv)));
    int q1 = (int)fminf(127.f, fmaxf(-128.f, rintf(v.y * inv)));
    int q2 = (int)fminf(127.f, fmaxf(-128.f, rintf(v.z * inv)));
    int q3 = (int)fminf(127.f, fmaxf(-128.f, rintf(v.w * inv)));
    return (q0 & 255) | ((q1 & 255) << 8) | ((q2 & 255) << 16) | ((q3 & 255) << 24);
}

// ---------- quantize to int8 codes: same y decode as k_absmax8 ----------
__global__ __launch_bounds__(256)
void k_quant8(const float* __restrict__ x,
              const float* __restrict__ w0, const float* __restrict__ w1,
              const float* __restrict__ w2, const float* __restrict__ w3,
              char* __restrict__ xq,
              char* __restrict__ o0, char* __restrict__ o1,
              char* __restrict__ o2, char* __restrict__ o3,
              const unsigned int* __restrict__ amax) {
    const int y = blockIdx.y;
    const float* p; char* o; int slot;
    if (y < 4) { p = x + (long)y * 1048576; o = xq + (long)y * 1048576; slot = 0; }
    else {
        int w = y - 4;
        p = (w == 0) ? w0 : (w == 1) ? w1 : (w == 2) ? w2 : w3;
        o = (w == 0) ? o0 : (w == 1) ? o1 : (w == 2) ? o2 : o3;
        slot = 1 + w;
    }
    float scale = fmaxf(__uint_as_float(amax[slot * ASLOT]) / 127.0f, 1e-8f);
    float inv = 1.0f / scale;
    const long n4 = 262144;
    long i = (long)blockIdx.x * blockDim.x + threadIdx.x;
    const long stride = (long)gridDim.x * blockDim.x;
    for (; i < n4; i += stride)
        ((unsigned int*)o)[i] = quant_pack4i(((const float4*)p)[i], inv);
}

// ---------- quantize f16 y -> int8 codes ----------
__global__ __launch_bounds__(256)
void k_quant_h(const _Float16* __restrict__ in, char* __restrict__ out,
               const unsigned int* __restrict__ amax, long n8) {
    float scale = fmaxf(__uint_as_float(*amax) / 127.0f, 1e-8f);
    float inv = 1.0f / scale;
    long i = (long)blockIdx.x * blockDim.x + threadIdx.x;
    const long stride = (long)gridDim.x * blockDim.x;
    for (; i < n8; i += stride) {
        f16x8 v = ((const f16x8*)in)[i];
        unsigned int lo = 0, hi = 0;
        #pragma unroll
        for (int u = 0; u < 4; ++u) {
            int q = (int)fminf(127.f, fmaxf(-128.f, rintf((float)v[u] * inv)));
            lo |= (unsigned int)(q & 255) << (8 * u);
        }
        #pragma unroll
        for (int u = 0; u < 4; ++u) {
            int q = (int)fminf(127.f, fmaxf(-128.f, rintf((float)v[4 + u] * inv)));
            hi |= (unsigned int)(q & 255) << (8 * u);
        }
        ((uint2*)out)[i] = make_uint2(lo, hi);
    }
}

// ---------- shared i8 GEMM core: 128x128 tile, BK=128, chunk-XOR swizzled LDS ----------
__device__ __forceinline__ void gemm_core8(const char* __restrict__ A,
                                           const char* __restrict__ Bw,
                                           int m0, int n0, int tid, i32x4 (&acc)[4][4]) {
    __shared__ char Asm[128 * 128];
    __shared__ char Bsm[128 * 128];
    const int lane = tid & 63, wid = tid >> 6;
    const int r16 = lane & 15, g = lane >> 4;
    const int wr = wid >> 1, wc = wid & 1;
    #pragma unroll
    for (int m = 0; m < 4; ++m)
        #pragma unroll
        for (int n = 0; n < 4; ++n) acc[m][n] = (i32x4){0, 0, 0, 0};
    for (int kt = 0; kt < 1024; kt += 128) {
        __syncthreads();
        #pragma unroll
        for (int s2 = 0; s2 < 4; ++s2) {
            int c = tid + s2 * 256;              // 0..1023 chunks of 16B per matrix
            int row = c >> 3, ch = c & 7;
            int chs = ch ^ (row & 7);            // pre-swizzled global source chunk
            gload_lds16(&A[(long)(m0 + row) * 1024 + kt + chs * 16], &Asm[c * 16]);
            gload_lds16(&Bw[(long)(n0 + row) * 1024 + kt + chs * 16], &Bsm[c * 16]);
        }
        __syncthreads();
        #pragma unroll
        for (int kk = 0; kk < 2; ++kk) {
            i32x4 af[4], bf[4];
            #pragma unroll
            for (int m = 0; m < 4; ++m) {
                int row = wr * 64 + m * 16 + r16;
                af[m] = *(const i32x4*)&Asm[row * 128 + (((kk * 4 + g) ^ (row & 7)) << 4)];
            }
            #pragma unroll
            for (int n = 0; n < 4; ++n) {
                int row = wc * 64 + n * 16 + r16;
                bf[n] = *(const i32x4*)&Bsm[row * 128 + (((kk * 4 + g) ^ (row & 7)) << 4)];
            }
            #pragma unroll
            for (int m = 0; m < 4; ++m)
                #pragma unroll
                for (int n = 0; n < 4; ++n)
                    acc[m][n] = __builtin_amdgcn_mfma_i32_16x16x64_i8(af[m], bf[n], acc[m][n], 0, 0, 0);
        }
    }
}

// ---------- fused QKV projection, XCD-swizzled 1D grid (768 blocks) ----------
// decode: xcd=L&7, t=L>>3; my=xcd*4+(t&3), nx=(t>>2)&7, z=t>>5  -> per-XCD: 4 A-panels + 1 W
__global__ __launch_bounds__(256)
void k_gemm_qkv(const char* __restrict__ A,
                const char* __restrict__ wq, const char* __restrict__ wk,
                const char* __restrict__ wv,
                const float* __restrict__ bq, const float* __restrict__ bk,
                const float* __restrict__ bv,
                const unsigned int* __restrict__ amax,
                _Float16* __restrict__ qo, _Float16* __restrict__ ko,
                _Float16* __restrict__ vto) {
    const int L = blockIdx.x;
    const int t = L >> 3;
    const int my = (L & 7) * 4 + (t & 3);
    const int nx = (t >> 2) & 7;
    const int z = t >> 5;
    const char* Bw = (z == 0) ? wq : (z == 1) ? wk : wv;
    const float* bias = (z == 0) ? bq : (z == 1) ? bk : bv;
    const int tid = threadIdx.x;
    const int m0 = my * 128, n0 = nx * 128;
    const int lane = tid & 63, wid = tid >> 6;
    const int r16 = lane & 15, g = lane >> 4;
    const int wr = wid >> 1, wc = wid & 1;

    i32x4 acc[4][4];
    gemm_core8(A, Bw, m0, n0, tid, acc);

    float sA = fmaxf(__uint_as_float(amax[0]) / 127.0f, 1e-8f);
    float sB = fmaxf(__uint_as_float(amax[(1 + z) * ASLOT]) / 127.0f, 1e-8f);
    float s = sA * sB;
    if (z < 2) {
        _Float16* out = (z == 0) ? qo : ko;
        #pragma unroll
        for (int m = 0; m < 4; ++m)
            #pragma unroll
            for (int n = 0; n < 4; ++n) {
                int col = n0 + wc * 64 + n * 16 + r16;
                float bcol = bias[col];
                int h = col >> 6, d = col & 63;
                #pragma unroll
                for (int r = 0; r < 4; ++r) {
                    int row = m0 + wr * 64 + m * 16 + g * 4 + r;
                    int b = row >> 11, tt = row & 2047;
                    out[(((long)(b * NH + h)) * T_SEQ + tt) * HD + d] =
                        (_Float16)((float)acc[m][n][r] * s + bcol);
                }
            }
    } else {
        #pragma unroll
        for (int m = 0; m < 4; ++m)
            #pragma unroll
            for (int n = 0; n < 4; ++n) {
                int col = n0 + wc * 64 + n * 16 + r16;
                float bcol = bias[col];
                int h = col >> 6, d = col & 63;
                int row0 = m0 + wr * 64 + m * 16 + g * 4;
                int b = row0 >> 11, tt = row0 & 2047;
                f16x4 pk;
                #pragma unroll
                for (int r = 0; r < 4; ++r) pk[r] = (_Float16)((float)acc[m][n][r] * s + bcol);
                *(f16x4*)&vto[(((long)(b * NH + h)) * HD + d) * T_SEQ + tt] = pk;
            }
    }
}

// ---------- output projection GEMM, i8, 128x64 tiles, BK=128, XCD-swizzled (512) ----------
__global__ __launch_bounds__(256)
void k_gemm_o(const char* __restrict__ A, const char* __restrict__ Bw,
              const float* __restrict__ bias,
              const unsigned int* __restrict__ amaxA, const unsigned int* __restrict__ amaxB,
              float* __restrict__ out) {
    __shared__ char Asm[128 * 128];
    __shared__ char Bsm[64 * 128];
    const int L = blockIdx.x;
    const int t = L >> 3;
    const int my = (L & 7) * 4 + (t & 3);
    const int nx = t >> 2;                 // 0..15
    const int tid = threadIdx.x;
    const int m0 = my * 128, n0 = nx * 64;
    const int lane = tid & 63, wid = tid >> 6;
    const int r16 = lane & 15, g = lane >> 4;
    const int wr = wid >> 1, wc = wid & 1;

    i32x4 acc[4][2];
    #pragma unroll
    for (int m = 0; m < 4; ++m)
        #pragma unroll
        for (int n = 0; n < 2; ++n) acc[m][n] = (i32x4){0, 0, 0, 0};

    for (int kt = 0; kt < 1024; kt += 128) {
        __syncthreads();
        #pragma unroll
        for (int s2 = 0; s2 < 4; ++s2) {
            int c = tid + s2 * 256;              // A: 1024 chunks
            int row = c >> 3, ch = c & 7;
            int chs = ch ^ (row & 7);
            gload_lds16(&A[(long)(m0 + row) * 1024 + kt + chs * 16], &Asm[c * 16]);
        }
        #pragma unroll
        for (int s2 = 0; s2 < 2; ++s2) {
            int c = tid + s2 * 256;              // B: 512 chunks
            int row = c >> 3, ch = c & 7;
            int chs = ch ^ (row & 7);
            gload_lds16(&Bw[(long)(n0 + row) * 1024 + kt + chs * 16], &Bsm[c * 16]);
        }
        __syncthreads();
        #pragma unroll
        for (int kk = 0; kk < 2; ++kk) {
            i32x4 af[4], bf[2];
            #pragma unroll
            for (int m = 0; m < 4; ++m) {
                int row = wr * 64 + m * 16 + r16;
                af[m] = *(const i32x4*)&Asm[row * 128 + (((kk * 4 + g) ^ (row & 7)) << 4)];
            }
            #pragma unroll
            for (int n = 0; n < 2; ++n) {
                int row = wc * 32 + n * 16 + r16;
                bf[n] = *(const i32x4*)&Bsm[row * 128 + (((kk * 4 + g) ^ (row & 7)) << 4)];
            }
            #pragma unroll
            for (int m = 0; m < 4; ++m)
                #pragma unroll
                for (int n = 0; n < 2; ++n)
                    acc[m][n] = __builtin_amdgcn_mfma_i32_16x16x64_i8(af[m], bf[n], acc[m][n], 0, 0, 0);
        }
    }

    float sA = fmaxf(__uint_as_float(*amaxA) / 127.0f, 1e-8f);
    float sB = fmaxf(__uint_as_float(*amaxB) / 127.0f, 1e-8f);
    float s = sA * sB;
    #pragma unroll
    for (int m = 0; m < 4; ++m)
        #pragma unroll
        for (int n = 0; n < 2; ++n) {
            int col = n0 + wc * 32 + n * 16 + r16;
            float bcol = bias[col];
            #pragma unroll
            for (int r = 0; r < 4; ++r) {
                int row = m0 + wr * 64 + m * 16 + g * 4 + r;
                out[(long)row * 1024 + col] = (float)acc[m][n][r] * s + bcol;
            }
        }
}

// softmax + P-write + PV for one m-pass (R11 proven version); MI is a literal.
#define SOFTPV(S, MI)                                                                   \
    {                                                                                   \
        float t0_ = fmaxf(fmaxf(S[0][0], S[0][1]), fmaxf(S[0][2], S[0][3]));            \
        float t1_ = fmaxf(fmaxf(S[1][0], S[1][1]), fmaxf(S[1][2], S[1][3]));            \
        float t2_ = fmaxf(fmaxf(S[2][0], S[2][1]), fmaxf(S[2][2], S[2][3]));            \
        float t3_ = fmaxf(fmaxf(S[3][0], S[3][1]), fmaxf(S[3][2], S[3][3]));            \
        float Ml = fmaxf(fmaxf(t0_, t1_), fmaxf(t2_, t3_));                             \
        if (__any(Ml > mrun[MI] + 11.5f)) {                                             \
            float M = Ml;                                                               \
            _Pragma("unroll")                                                           \
            for (int off = 1; off < 64; off <<= 1) M = fmaxf(M, __shfl_xor(M, off));    \
            float corr = fexp2(mrun[MI] - M);                                           \
            _Pragma("unroll")                                                           \
            for (int r = 0; r < 4; ++r) lacc[MI][r] *= corr;                            \
            _Pragma("unroll")                                                           \
            for (int nb = 0; nb < 4; ++nb)                                              \
                _Pragma("unroll")                                                       \
                for (int r = 0; r < 4; ++r) oacc[MI][nb][r] *= corr;                    \
            mrun[MI] = M;                                                               \
        }                                                                               \
        _Pragma("unroll")                                                               \
        for (int nb = 0; nb < 4; ++nb)                                                  \
            _Pragma("unroll")                                                           \
            for (int r = 0; r < 4; ++r) {                                               \
                float pv = fexp2(S[nb][r] - mrun[MI]);                                  \
                lacc[MI][r] += pv;                                                      \
                int row = g * 4 + r, col = nb * 16 + r16;                               \
                int c8 = col >> 3;                                                      \
                Psm[wid][row * 64 + ((c8 ^ (row & 7)) << 3) + (col & 7)] = (_Float16)pv;\
            }                                                                           \
        f16x8 pa0 = *(const f16x8*)&Psm[wid][r16 * 64 + (((g)     ^ (r16 & 7)) << 3)];  \
        f16x8 pa1 = *(const f16x8*)&Psm[wid][r16 * 64 + (((4 + g) ^ (r16 & 7)) << 3)];  \
        __builtin_amdgcn_s_setprio(1);                                                  \
        _Pragma("unroll")                                                               \
        for (int nb = 0; nb < 4; ++nb) {                                                \
            int row = nb * 16 + r16;                                                    \
            f16x8 vb0 = *(const f16x8*)&Vd[row * 64 + (((g)     ^ (row & 7)) << 3)];    \
            f16x8 vb1 = *(const f16x8*)&Vd[row * 64 + (((4 + g) ^ (row & 7)) << 3)];    \
            oacc[MI][nb] = __builtin_amdgcn_mfma_f32_16x16x32_f16(pa0, vb0, oacc[MI][nb], 0, 0, 0); \
            oacc[MI][nb] = __builtin_amdgcn_mfma_f32_16x16x32_f16(pa1, vb1, oacc[MI][nb], 0, 0, 0); \
        }                                                                               \
        __builtin_amdgcn_s_setprio(0);                                                  \
    }

// ---------- flash attention: single-buffer K/V, 5-way split-K (1280 blocks = 5/CU) ----------
// QBLK=128 time-multiplexed m-passes, pair (Jh=15-p, Jl=p), XCD bh grouping.
// L decode: bh=(L&7)*4+((L>>3)&3); rest=L>>5 (0..39): p=rest/5, z=rest%5.
// Slices [34z/5, 34(z+1)/5): 6,7,7,7,7 steps. __launch_bounds__(256,5) pins VGPR<=102.
__global__ __launch_bounds__(256, 5)
void k_attn(const _Float16* __restrict__ q, const _Float16* __restrict__ kk,
            const _Float16* __restrict__ vt,
            _Float16* __restrict__ Op, float2* __restrict__ ML) {
    __shared__ _Float16 Kd[4096];          // [64][64] linear, chunk-XOR swizzled
    __shared__ _Float16 Vd[4096];
    __shared__ _Float16 Psm[4][1024];      // [16][64] per wave, time-shared across m

    const int L = blockIdx.x;
    const int bh = (L & 7) * 4 + ((L >> 3) & 3);
    const int rest = L >> 5;               // 0..39
    const int p = rest / NZ, z = rest % NZ;
    const int tid = threadIdx.x, wid = tid >> 6, lane = tid & 63;
    const int r16 = lane & 15, g = lane >> 4;
    const long base = (long)bh * T_SEQ * HD;
    const long vbase = (long)bh * HD * T_SEQ;
    const int nkh = 2 * (15 - p) + 2;      // K-steps in Jh sub (Jh = 15-p)
    const int a = (34 * z) / NZ, b2 = (34 * (z + 1)) / NZ;

    auto STAGE = [&](int jt) {
        const _Float16* kp = kk + base + (long)jt * 64 * HD;
        const _Float16* vp = vt + vbase + jt * 64;
        #pragma unroll
        for (int s2 = 0; s2 < 2; ++s2) {
            int slot = tid + s2 * 256;           // linear LDS chunk (dest = base + lane*16)
            int row = slot >> 3;
            int ch = (slot & 7) ^ (row & 7);     // pre-swizzled global source chunk
            gload_lds16(kp + row * HD + ch * 8, &Kd[slot * 8]);
            gload_lds16(vp + (long)row * T_SEQ + ch * 8, &Vd[slot * 8]);
        }
    };

    #pragma unroll 1
    for (int sub = 0; sub < 2; ++sub) {
        const int J = sub ? p : (15 - p);
        const int nk = 2 * J + 2;
        const int lo = sub ? max(a - nkh, 0) : a;
        const int hi = sub ? max(b2 - nkh, 0) : min(b2, nk);
        const int t0 = J * 128;
        const long prow = (long)(z * 32 + bh) * T_SEQ + t0;

        if (lo >= hi) {                        // slice doesn't touch this Q-tile: sentinels
            f16x8 zz = {};
            #pragma unroll 1
            for (int i = tid; i < 1024; i += 256) {      // 128 rows x 8 chunks
                int row = i >> 3, ch = i & 7;
                *(f16x8*)&Op[(prow + row) * HD + ch * 8] = zz;
            }
            if (tid < 128) ML[prow + tid] = make_float2(-INFINITY, 0.f);
            continue;
        }

        f16x8 qf[2][2];
        #pragma unroll
        for (int m = 0; m < 2; ++m) {
            const _Float16* qp = q + base + (long)(t0 + m * 64 + wid * 16 + r16) * HD + g * 8;
            qf[m][0] = *(const f16x8*)qp;
            qf[m][1] = *(const f16x8*)(qp + 32);
            #pragma unroll
            for (int u = 0; u < 8; ++u) {      // fold 1/sqrt(64)*log2(e): log2-domain scores
                qf[m][0][u] *= (_Float16)0.18033688f;
                qf[m][1][u] *= (_Float16)0.18033688f;
            }
        }
        float mrun[2] = {-INFINITY, -INFINITY};
        float lacc[2][4] = {{0.f, 0.f, 0.f, 0.f}, {0.f, 0.f, 0.f, 0.f}};
        f32x4 oacc[2][4];
        #pragma unroll
        for (int m = 0; m < 2; ++m)
            #pragma unroll
            for (int nb = 0; nb < 4; ++nb) oacc[m][nb] = (f32x4){0.f, 0.f, 0.f, 0.f};

        for (int jt = lo; jt < hi; ++jt) {
            __syncthreads();                   // all waves done with previous K/V tile
            STAGE(jt);
            __syncthreads();                   // vmcnt drained: Kd/Vd ready

            const bool skip0 = (jt == 2 * J + 1);      // m=0 fully masked on this step
            #pragma unroll
            for (int m = 0; m < 2; ++m) {
                if (m == 0 && skip0) continue;
                f32x4 s[4];
                __builtin_amdgcn_s_setprio(1);
                #pragma unroll
                for (int nb = 0; nb < 4; ++nb) {
                    int row = nb * 16 + r16;
                    f16x8 kb0 = *(const f16x8*)&Kd[row * 64 + (((g)     ^ (row & 7)) << 3)];
                    f16x8 kb1 = *(const f16x8*)&Kd[row * 64 + (((4 + g) ^ (row & 7)) << 3)];
                    f32x4 a0 = (f32x4){0.f, 0.f, 0.f, 0.f};
                    a0 = __builtin_amdgcn_mfma_f32_16x16x32_f16(qf[m][0], kb0, a0, 0, 0, 0);
                    a0 = __builtin_amdgcn_mfma_f32_16x16x32_f16(qf[m][1], kb1, a0, 0, 0, 0);
                    s[nb] = a0;
                }
                __builtin_amdgcn_s_setprio(0);
                if (jt == 2 * J + m) {         // diagonal tile for this m-pass
                    #pragma unroll
                    for (int nb = 0; nb < 4; ++nb)
                        #pragma unroll
                        for (int r = 0; r < 4; ++r)
                            if (nb * 16 + r16 > wid * 16 + g * 4 + r) s[nb][r] = -INFINITY;
                }
                SOFTPV(s, m)
            }
        }
        // epilogue: per-m row sums; l==0 rows (m-pass never ran) -> sentinel
        #pragma unroll
        for (int m = 0; m < 2; ++m) {
            float lsum[4], linv[4];
            #pragma unroll
            for (int r = 0; r < 4; ++r) {
                float Lr = lacc[m][r];
                #pragma unroll
                for (int off = 1; off < 16; off <<= 1) Lr += __shfl_xor(Lr, off);
                lsum[r] = Lr;
                linv[r] = (Lr > 0.f) ? 1.f / Lr : 0.f;
            }
            #pragma unroll
            for (int nb = 0; nb < 4; ++nb)
                #pragma unroll
                for (int r = 0; r < 4; ++r)
                    Op[(prow + m * 64 + wid * 16 + g * 4 + r) * HD + nb * 16 + r16] =
                        (_Float16)(oacc[m][nb][r] * linv[r]);
            if (r16 == 0)
                #pragma unroll
                for (int r = 0; r < 4; ++r)
                    ML[prow + m * 64 + wid * 16 + g * 4 + r] =
                        make_float2(lsum[r] > 0.f ? mrun[m] : -INFINITY, lsum[r]);
        }
    }
}

// ---------- combine NZ split partials -> y f16 (vectorized); block-reduced absmax ----------
__global__ __launch_bounds__(256)
void k_combine(const _Float16* __restrict__ Op, const float2* __restrict__ ML,
               _Float16* __restrict__ y, unsigned int* __restrict__ amax5) {
    __shared__ float wred[4];
    const int tid = threadIdx.x;
    const int c8 = (tid & 7) * 8;          // col start (8 f16)
    const int rsub = tid >> 3;             // 0..31
    float bmax = 0.f;
    #pragma unroll 1
    for (int it = 0; it < 8; ++it) {
        int row = blockIdx.x * 256 + it * 32 + rsub;     // 0..65535 = bh*2048 + t
        float2 ml[NZ];
        #pragma unroll
        for (int zz = 0; zz < NZ; ++zz) ml[zz] = ML[row + zz * 65536];
        float M = ml[0].x;
        #pragma unroll
        for (int zz = 1; zz < NZ; ++zz) M = fmaxf(M, ml[zz].x);
        float w[NZ]; float den = 0.f;
        #pragma unroll
        for (int zz = 0; zz < NZ; ++zz) { w[zz] = fexp2(ml[zz].x - M) * ml[zz].y; den += w[zz]; }
        float inv = 1.f / den;
        f16x8 o[NZ];
        #pragma unroll
        for (int zz = 0; zz < NZ; ++zz)
            o[zz] = *(const f16x8*)&Op[(long)(row + zz * 65536) * HD + c8];
        f16x8 res;
        #pragma unroll
        for (int u = 0; u < 8; ++u) {
            float num = 0.f;
            #pragma unroll
            for (int zz = 0; zz < NZ; ++zz) num += w[zz] * (float)o[zz][u];
            float val = num * inv;
            res[u] = (_Float16)val;
            bmax = fmaxf(bmax, fabsf(val));
        }
        int bh = row >> 11, t = row & 2047;
        *(f16x8*)&y[((long)((bh >> 4) * T_SEQ + t)) * D_MODEL + (bh & 15) * HD + c8] = res;
    }
    #pragma unroll
    for (int off = 1; off < 64; off <<= 1) bmax = fmaxf(bmax, __shfl_xor(bmax, off));
    if ((tid & 63) == 0) wred[tid >> 6] = bmax;
    __syncthreads();
    if (tid == 0) {
        float m = fmaxf(fmaxf(wred[0], wred[1]), fmaxf(wred[2], wred[3]));
        if (m > 0.f) atomicMax(amax5, __float_as_uint(m));
    }
}

// ---------------- launch ----------------
extern "C" void kernel_launch(void* const* d_in, const int* in_sizes, int n_in,
                              void* d_out, int out_size, void* d_ws, size_t ws_size,
                              hipStream_t stream) {
    const float* x  = (const float*)d_in[0];
    const float* Wq = (const float*)d_in[1];
    const float* bq = (const float*)d_in[2];
    const float* Wk = (const float*)d_in[3];
    const float* bk = (const float*)d_in[4];
    const float* Wv = (const float*)d_in[5];
    const float* bv = (const float*)d_in[6];
    const float* Wo = (const float*)d_in[7];
    const float* bo = (const float*)d_in[8];

    char* ws = (char*)d_ws;
    unsigned int* amax = (unsigned int*)ws;                     // slots at i*ASLOT (128 B apart)
    char* xq8 = ws + 4096;                                      // 4 MB
    char* wq8 = xq8 + 4194304L;                                 // 1 MB each
    char* wk8 = wq8 + 1048576L;
    char* wv8 = wk8 + 1048576L;
    char* wo8 = wv8 + 1048576L;
    char* p2 = ws + 4096 + 8388608L;
    _Float16* qh  = (_Float16*)p2;                              // 8 MB each
    _Float16* kh  = (_Float16*)(p2 + 8388608L);
    _Float16* vth = (_Float16*)(p2 + 16777216L);
    _Float16* ybh = (_Float16*)(p2 + 25165824L);                // 8 MB f16
    char*     yq8 = p2 + 33554432L;                             // 4 MB
    _Float16* Opart = (_Float16*)(p2 + 37748736L);              // 40 MB (5 slots)
    float2*   MLp   = (float2*)(p2 + 37748736L + 41943040L);    // 2.5 MB

    const long NY8 = (long)NB * T_SEQ * D_MODEL / 8;            // 524288

    (void)hipMemsetAsync(amax, 0, 1024, stream);
    k_absmax8<<<dim3(32, 8), 256, 0, stream>>>(x, Wq, Wk, Wv, Wo, amax);
    k_quant8<<<dim3(128, 8), 256, 0, stream>>>(x, Wq, Wk, Wv, Wo,
                                               xq8, wq8, wk8, wv8, wo8, amax);
    k_gemm_qkv<<<768, 256, 0, stream>>>(xq8, wq8, wk8, wv8, bq, bk, bv,
                                        amax, qh, kh, vth);
    k_attn<<<1280, 256, 0, stream>>>(qh, kh, vth, Opart, MLp);
    k_combine<<<256, 256, 0, stream>>>(Opart, MLp, ybh, amax + 5 * ASLOT);
    k_quant_h<<<512, 256, 0, stream>>>(ybh, yq8, amax + 5 * ASLOT, NY8);
    k_gemm_o<<<512, 256, 0, stream>>>(yq8, wo8, bo, amax + 5 * ASLOT, amax + 4 * ASLOT,
                                      (float*)d_out);
}

// Round 19
// 131.255 us; speedup vs baseline: 1.3662x; 1.3662x over previous
//
#include <hip/hip_runtime.h>
#include <hip/hip_fp16.h>

#define T_SEQ 2048
#define D_MODEL 1024
#define NB 2
#define NH 16
#define HD 64
#define NZ 5

using f16x8 = __attribute__((ext_vector_type(8))) _Float16;
using f16x4 = __attribute__((ext_vector_type(4))) _Float16;
using f32x4 = __attribute__((ext_vector_type(4))) float;
using i32x4 = __attribute__((ext_vector_type(4))) int;

// amax slots padded to 128 B (32 uints) apart: one cache line per slot
#define ASLOT 32

__device__ __forceinline__ float fexp2(float x) { return __builtin_amdgcn_exp2f(x); }

__device__ __forceinline__ void gload_lds16(const void* g, void* l) {
    __builtin_amdgcn_global_load_lds((const __attribute__((address_space(1))) void*)g,
                                     (__attribute__((address_space(3))) void*)l, 16, 0, 0);
}

// ---------- absmax: y<4 -> x slice y (slot 0); y>=4 -> W[y-4] (slot 1+y-4) ----------
__global__ __launch_bounds__(256)
void k_absmax8(const float* __restrict__ x,
               const float* __restrict__ w0, const float* __restrict__ w1,
               const float* __restrict__ w2, const float* __restrict__ w3,
               unsigned int* __restrict__ amax) {
    __shared__ float wred[4];
    const int y = blockIdx.y;
    const float* p; int slot;
    if (y < 4) { p = x + (long)y * 1048576; slot = 0; }
    else { int w = y - 4; p = (w == 0) ? w0 : (w == 1) ? w1 : (w == 2) ? w2 : w3; slot = 1 + w; }
    const float4* p4 = (const float4*)p;
    const long i0 = (long)blockIdx.x * 256 + threadIdx.x;   // 0..8191
    float m = 0.f;
    #pragma unroll 4
    for (int it = 0; it < 32; ++it) {                       // 32*8192 = 262144 float4
        float4 v = p4[i0 + (long)it * 8192];
        m = fmaxf(fmaxf(fmaxf(fabsf(v.x), fabsf(v.y)), fmaxf(fabsf(v.z), fabsf(v.w))), m);
    }
    #pragma unroll
    for (int off = 1; off < 64; off <<= 1) m = fmaxf(m, __shfl_xor(m, off));
    if ((threadIdx.x & 63) == 0) wred[threadIdx.x >> 6] = m;
    __syncthreads();
    if (threadIdx.x == 0) {
        float mm = fmaxf(fmaxf(wred[0], wred[1]), fmaxf(wred[2], wred[3]));
        if (mm > 0.f) atomicMax(amax + slot * ASLOT, __float_as_uint(mm));
    }
}

__device__ __forceinline__ unsigned int quant_pack4i(float4 v, float inv) {
    int q0 = (int)fminf(127.f, fmaxf(-128.f, rintf(v.x * inv)));
    int q1 = (int)fminf(127.f, fmaxf(-128.f, rintf(v.y * inv)));
    int q2 = (int)fminf(127.f, fmaxf(-128.f, rintf(v.z * inv)));
    int q3 = (int)fminf(127.f, fmaxf(-128.f, rintf(v.w * inv)));
    return (q0 & 255) | ((q1 & 255) << 8) | ((q2 & 255) << 16) | ((q3 & 255) << 24);
}

// ---------- quantize to int8 codes: same y decode as k_absmax8 ----------
__global__ __launch_bounds__(256)
void k_quant8(const float* __restrict__ x,
              const float* __restrict__ w0, const float* __restrict__ w1,
              const float* __restrict__ w2, const float* __restrict__ w3,
              char* __restrict__ xq,
              char* __restrict__ o0, char* __restrict__ o1,
              char* __restrict__ o2, char* __restrict__ o3,
              const unsigned int* __restrict__ amax) {
    const int y = blockIdx.y;
    const float* p; char* o; int slot;
    if (y < 4) { p = x + (long)y * 1048576; o = xq + (long)y * 1048576; slot = 0; }
    else {
        int w = y - 4;
        p = (w == 0) ? w0 : (w == 1) ? w1 : (w == 2) ? w2 : w3;
        o = (w == 0) ? o0 : (w == 1) ? o1 : (w == 2) ? o2 : o3;
        slot = 1 + w;
    }
    float scale = fmaxf(__uint_as_float(amax[slot * ASLOT]) / 127.0f, 1e-8f);
    float inv = 1.0f / scale;
    const long n4 = 262144;
    long i = (long)blockIdx.x * blockDim.x + threadIdx.x;
    const long stride = (long)gridDim.x * blockDim.x;
    for (; i < n4; i += stride)
        ((unsigned int*)o)[i] = quant_pack4i(((const float4*)p)[i], inv);
}

// ---------- quantize f16 y -> int8 codes ----------
__global__ __launch_bounds__(256)
void k_quant_h(const _Float16* __restrict__ in, char* __restrict__ out,
               const unsigned int* __restrict__ amax, long n8) {
    float scale = fmaxf(__uint_as_float(*amax) / 127.0f, 1e-8f);
    float inv = 1.0f / scale;
    long i = (long)blockIdx.x * blockDim.x + threadIdx.x;
    const long stride = (long)gridDim.x * blockDim.x;
    for (; i < n8; i += stride) {
        f16x8 v = ((const f16x8*)in)[i];
        unsigned int lo = 0, hi = 0;
        #pragma unroll
        for (int u = 0; u < 4; ++u) {
            int q = (int)fminf(127.f, fmaxf(-128.f, rintf((float)v[u] * inv)));
            lo |= (unsigned int)(q & 255) << (8 * u);
        }
        #pragma unroll
        for (int u = 0; u < 4; ++u) {
            int q = (int)fminf(127.f, fmaxf(-128.f, rintf((float)v[4 + u] * inv)));
            hi |= (unsigned int)(q & 255) << (8 * u);
        }
        ((uint2*)out)[i] = make_uint2(lo, hi);
    }
}

// ---------- shared i8 GEMM core: 128x128 tile, BK=128, chunk-XOR swizzled LDS ----------
__device__ __forceinline__ void gemm_core8(const char* __restrict__ A,
                                           const char* __restrict__ Bw,
                                           int m0, int n0, int tid, i32x4 (&acc)[4][4]) {
    __shared__ char Asm[128 * 128];
    __shared__ char Bsm[128 * 128];
    const int lane = tid & 63, wid = tid >> 6;
    const int r16 = lane & 15, g = lane >> 4;
    const int wr = wid >> 1, wc = wid & 1;
    #pragma unroll
    for (int m = 0; m < 4; ++m)
        #pragma unroll
        for (int n = 0; n < 4; ++n) acc[m][n] = (i32x4){0, 0, 0, 0};
    for (int kt = 0; kt < 1024; kt += 128) {
        __syncthreads();
        #pragma unroll
        for (int s2 = 0; s2 < 4; ++s2) {
            int c = tid + s2 * 256;              // 0..1023 chunks of 16B per matrix
            int row = c >> 3, ch = c & 7;
            int chs = ch ^ (row & 7);            // pre-swizzled global source chunk
            gload_lds16(&A[(long)(m0 + row) * 1024 + kt + chs * 16], &Asm[c * 16]);
            gload_lds16(&Bw[(long)(n0 + row) * 1024 + kt + chs * 16], &Bsm[c * 16]);
        }
        __syncthreads();
        #pragma unroll
        for (int kk = 0; kk < 2; ++kk) {
            i32x4 af[4], bf[4];
            #pragma unroll
            for (int m = 0; m < 4; ++m) {
                int row = wr * 64 + m * 16 + r16;
                af[m] = *(const i32x4*)&Asm[row * 128 + (((kk * 4 + g) ^ (row & 7)) << 4)];
            }
            #pragma unroll
            for (int n = 0; n < 4; ++n) {
                int row = wc * 64 + n * 16 + r16;
                bf[n] = *(const i32x4*)&Bsm[row * 128 + (((kk * 4 + g) ^ (row & 7)) << 4)];
            }
            #pragma unroll
            for (int m = 0; m < 4; ++m)
                #pragma unroll
                for (int n = 0; n < 4; ++n)
                    acc[m][n] = __builtin_amdgcn_mfma_i32_16x16x64_i8(af[m], bf[n], acc[m][n], 0, 0, 0);
        }
    }
}

// ---------- fused QKV projection, XCD-swizzled 1D grid (768 blocks) ----------
// decode: xcd=L&7, t=L>>3; my=xcd*4+(t&3), nx=(t>>2)&7, z=t>>5  -> per-XCD: 4 A-panels + 1 W
__global__ __launch_bounds__(256)
void k_gemm_qkv(const char* __restrict__ A,
                const char* __restrict__ wq, const char* __restrict__ wk,
                const char* __restrict__ wv,
                const float* __restrict__ bq, const float* __restrict__ bk,
                const float* __restrict__ bv,
                const unsigned int* __restrict__ amax,
                _Float16* __restrict__ qo, _Float16* __restrict__ ko,
                _Float16* __restrict__ vto) {
    const int L = blockIdx.x;
    const int t = L >> 3;
    const int my = (L & 7) * 4 + (t & 3);
    const int nx = (t >> 2) & 7;
    const int z = t >> 5;
    const char* Bw = (z == 0) ? wq : (z == 1) ? wk : wv;
    const float* bias = (z == 0) ? bq : (z == 1) ? bk : bv;
    const int tid = threadIdx.x;
    const int m0 = my * 128, n0 = nx * 128;
    const int lane = tid & 63, wid = tid >> 6;
    const int r16 = lane & 15, g = lane >> 4;
    const int wr = wid >> 1, wc = wid & 1;

    i32x4 acc[4][4];
    gemm_core8(A, Bw, m0, n0, tid, acc);

    float sA = fmaxf(__uint_as_float(amax[0]) / 127.0f, 1e-8f);
    float sB = fmaxf(__uint_as_float(amax[(1 + z) * ASLOT]) / 127.0f, 1e-8f);
    float s = sA * sB;
    if (z < 2) {
        _Float16* out = (z == 0) ? qo : ko;
        #pragma unroll
        for (int m = 0; m < 4; ++m)
            #pragma unroll
            for (int n = 0; n < 4; ++n) {
                int col = n0 + wc * 64 + n * 16 + r16;
                float bcol = bias[col];
                int h = col >> 6, d = col & 63;
                #pragma unroll
                for (int r = 0; r < 4; ++r) {
                    int row = m0 + wr * 64 + m * 16 + g * 4 + r;
                    int b = row >> 11, tt = row & 2047;
                    out[(((long)(b * NH + h)) * T_SEQ + tt) * HD + d] =
                        (_Float16)((float)acc[m][n][r] * s + bcol);
                }
            }
    } else {
        #pragma unroll
        for (int m = 0; m < 4; ++m)
            #pragma unroll
            for (int n = 0; n < 4; ++n) {
                int col = n0 + wc * 64 + n * 16 + r16;
                float bcol = bias[col];
                int h = col >> 6, d = col & 63;
                int row0 = m0 + wr * 64 + m * 16 + g * 4;
                int b = row0 >> 11, tt = row0 & 2047;
                f16x4 pk;
                #pragma unroll
                for (int r = 0; r < 4; ++r) pk[r] = (_Float16)((float)acc[m][n][r] * s + bcol);
                *(f16x4*)&vto[(((long)(b * NH + h)) * HD + d) * T_SEQ + tt] = pk;
            }
    }
}

// ---------- output projection GEMM, i8, 128x64 tiles, BK=128, XCD-swizzled (512) ----------
__global__ __launch_bounds__(256)
void k_gemm_o(const char* __restrict__ A, const char* __restrict__ Bw,
              const float* __restrict__ bias,
              const unsigned int* __restrict__ amaxA, const unsigned int* __restrict__ amaxB,
              float* __restrict__ out) {
    __shared__ char Asm[128 * 128];
    __shared__ char Bsm[64 * 128];
    const int L = blockIdx.x;
    const int t = L >> 3;
    const int my = (L & 7) * 4 + (t & 3);
    const int nx = t >> 2;                 // 0..15
    const int tid = threadIdx.x;
    const int m0 = my * 128, n0 = nx * 64;
    const int lane = tid & 63, wid = tid >> 6;
    const int r16 = lane & 15, g = lane >> 4;
    const int wr = wid >> 1, wc = wid & 1;

    i32x4 acc[4][2];
    #pragma unroll
    for (int m = 0; m < 4; ++m)
        #pragma unroll
        for (int n = 0; n < 2; ++n) acc[m][n] = (i32x4){0, 0, 0, 0};

    for (int kt = 0; kt < 1024; kt += 128) {
        __syncthreads();
        #pragma unroll
        for (int s2 = 0; s2 < 4; ++s2) {
            int c = tid + s2 * 256;              // A: 1024 chunks
            int row = c >> 3, ch = c & 7;
            int chs = ch ^ (row & 7);
            gload_lds16(&A[(long)(m0 + row) * 1024 + kt + chs * 16], &Asm[c * 16]);
        }
        #pragma unroll
        for (int s2 = 0; s2 < 2; ++s2) {
            int c = tid + s2 * 256;              // B: 512 chunks
            int row = c >> 3, ch = c & 7;
            int chs = ch ^ (row & 7);
            gload_lds16(&Bw[(long)(n0 + row) * 1024 + kt + chs * 16], &Bsm[c * 16]);
        }
        __syncthreads();
        #pragma unroll
        for (int kk = 0; kk < 2; ++kk) {
            i32x4 af[4], bf[2];
            #pragma unroll
            for (int m = 0; m < 4; ++m) {
                int row = wr * 64 + m * 16 + r16;
                af[m] = *(const i32x4*)&Asm[row * 128 + (((kk * 4 + g) ^ (row & 7)) << 4)];
            }
            #pragma unroll
            for (int n = 0; n < 2; ++n) {
                int row = wc * 32 + n * 16 + r16;
                bf[n] = *(const i32x4*)&Bsm[row * 128 + (((kk * 4 + g) ^ (row & 7)) << 4)];
            }
            #pragma unroll
            for (int m = 0; m < 4; ++m)
                #pragma unroll
                for (int n = 0; n < 2; ++n)
                    acc[m][n] = __builtin_amdgcn_mfma_i32_16x16x64_i8(af[m], bf[n], acc[m][n], 0, 0, 0);
        }
    }

    float sA = fmaxf(__uint_as_float(*amaxA) / 127.0f, 1e-8f);
    float sB = fmaxf(__uint_as_float(*amaxB) / 127.0f, 1e-8f);
    float s = sA * sB;
    #pragma unroll
    for (int m = 0; m < 4; ++m)
        #pragma unroll
        for (int n = 0; n < 2; ++n) {
            int col = n0 + wc * 32 + n * 16 + r16;
            float bcol = bias[col];
            #pragma unroll
            for (int r = 0; r < 4; ++r) {
                int row = m0 + wr * 64 + m * 16 + g * 4 + r;
                out[(long)row * 1024 + col] = (float)acc[m][n][r] * s + bcol;
            }
        }
}

// softmax + P-write + PV for one m-pass (R11 proven version); MI is a literal.
#define SOFTPV(S, MI)                                                                   \
    {                                                                                   \
        float t0_ = fmaxf(fmaxf(S[0][0], S[0][1]), fmaxf(S[0][2], S[0][3]));            \
        float t1_ = fmaxf(fmaxf(S[1][0], S[1][1]), fmaxf(S[1][2], S[1][3]));            \
        float t2_ = fmaxf(fmaxf(S[2][0], S[2][1]), fmaxf(S[2][2], S[2][3]));            \
        float t3_ = fmaxf(fmaxf(S[3][0], S[3][1]), fmaxf(S[3][2], S[3][3]));            \
        float Ml = fmaxf(fmaxf(t0_, t1_), fmaxf(t2_, t3_));                             \
        if (__any(Ml > mrun[MI] + 11.5f)) {                                             \
            float M = Ml;                                                               \
            _Pragma("unroll")                                                           \
            for (int off = 1; off < 64; off <<= 1) M = fmaxf(M, __shfl_xor(M, off));    \
            float corr = fexp2(mrun[MI] - M);                                           \
            _Pragma("unroll")                                                           \
            for (int r = 0; r < 4; ++r) lacc[MI][r] *= corr;                            \
            _Pragma("unroll")                                                           \
            for (int nb = 0; nb < 4; ++nb)                                              \
                _Pragma("unroll")                                                       \
                for (int r = 0; r < 4; ++r) oacc[MI][nb][r] *= corr;                    \
            mrun[MI] = M;                                                               \
        }                                                                               \
        _Pragma("unroll")                                                               \
        for (int nb = 0; nb < 4; ++nb)                                                  \
            _Pragma("unroll")                                                           \
            for (int r = 0; r < 4; ++r) {                                               \
                float pv = fexp2(S[nb][r] - mrun[MI]);                                  \
                lacc[MI][r] += pv;                                                      \
                int row = g * 4 + r, col = nb * 16 + r16;                               \
                int c8 = col >> 3;                                                      \
                Psm[wid][row * 64 + ((c8 ^ (row & 7)) << 3) + (col & 7)] = (_Float16)pv;\
            }                                                                           \
        f16x8 pa0 = *(const f16x8*)&Psm[wid][r16 * 64 + (((g)     ^ (r16 & 7)) << 3)];  \
        f16x8 pa1 = *(const f16x8*)&Psm[wid][r16 * 64 + (((4 + g) ^ (r16 & 7)) << 3)];  \
        __builtin_amdgcn_s_setprio(1);                                                  \
        _Pragma("unroll")                                                               \
        for (int nb = 0; nb < 4; ++nb) {                                                \
            int row = nb * 16 + r16;                                                    \
            f16x8 vb0 = *(const f16x8*)&Vd[row * 64 + (((g)     ^ (row & 7)) << 3)];    \
            f16x8 vb1 = *(const f16x8*)&Vd[row * 64 + (((4 + g) ^ (row & 7)) << 3)];    \
            oacc[MI][nb] = __builtin_amdgcn_mfma_f32_16x16x32_f16(pa0, vb0, oacc[MI][nb], 0, 0, 0); \
            oacc[MI][nb] = __builtin_amdgcn_mfma_f32_16x16x32_f16(pa1, vb1, oacc[MI][nb], 0, 0, 0); \
        }                                                                               \
        __builtin_amdgcn_s_setprio(0);                                                  \
    }

// ---------- flash attention: single-buffer K/V, 5-way split-K (1280 blocks = 5/CU) ----------
// QBLK=128 time-multiplexed m-passes, pair (Jh=15-p, Jl=p), XCD bh grouping.
// L decode: bh=(L&7)*4+((L>>3)&3); rest=L>>5 (0..39): p=rest/5, z=rest%5.
// Slices [34z/5, 34(z+1)/5): 6,7,7,7,7 steps. Default bounds: allocator free (VGPR ~100
// natively admits 5 waves/SIMD; R18's (256,5) clamp to 48 VGPR caused the spill storm).
__global__ __launch_bounds__(256)
void k_attn(const _Float16* __restrict__ q, const _Float16* __restrict__ kk,
            const _Float16* __restrict__ vt,
            _Float16* __restrict__ Op, float2* __restrict__ ML) {
    __shared__ _Float16 Kd[4096];          // [64][64] linear, chunk-XOR swizzled
    __shared__ _Float16 Vd[4096];
    __shared__ _Float16 Psm[4][1024];      // [16][64] per wave, time-shared across m

    const int L = blockIdx.x;
    const int bh = (L & 7) * 4 + ((L >> 3) & 3);
    const int rest = L >> 5;               // 0..39
    const int p = rest / NZ, z = rest % NZ;
    const int tid = threadIdx.x, wid = tid >> 6, lane = tid & 63;
    const int r16 = lane & 15, g = lane >> 4;
    const long base = (long)bh * T_SEQ * HD;
    const long vbase = (long)bh * HD * T_SEQ;
    const int nkh = 2 * (15 - p) + 2;      // K-steps in Jh sub (Jh = 15-p)
    const int a = (34 * z) / NZ, b2 = (34 * (z + 1)) / NZ;

    auto STAGE = [&](int jt) {
        const _Float16* kp = kk + base + (long)jt * 64 * HD;
        const _Float16* vp = vt + vbase + jt * 64;
        #pragma unroll
        for (int s2 = 0; s2 < 2; ++s2) {
            int slot = tid + s2 * 256;           // linear LDS chunk (dest = base + lane*16)
            int row = slot >> 3;
            int ch = (slot & 7) ^ (row & 7);     // pre-swizzled global source chunk
            gload_lds16(kp + row * HD + ch * 8, &Kd[slot * 8]);
            gload_lds16(vp + (long)row * T_SEQ + ch * 8, &Vd[slot * 8]);
        }
    };

    #pragma unroll 1
    for (int sub = 0; sub < 2; ++sub) {
        const int J = sub ? p : (15 - p);
        const int nk = 2 * J + 2;
        const int lo = sub ? max(a - nkh, 0) : a;
        const int hi = sub ? max(b2 - nkh, 0) : min(b2, nk);
        const int t0 = J * 128;
        const long prow = (long)(z * 32 + bh) * T_SEQ + t0;

        if (lo >= hi) {                        // slice doesn't touch this Q-tile: sentinels
            f16x8 zz = {};
            #pragma unroll 1
            for (int i = tid; i < 1024; i += 256) {      // 128 rows x 8 chunks
                int row = i >> 3, ch = i & 7;
                *(f16x8*)&Op[(prow + row) * HD + ch * 8] = zz;
            }
            if (tid < 128) ML[prow + tid] = make_float2(-INFINITY, 0.f);
            continue;
        }

        f16x8 qf[2][2];
        #pragma unroll
        for (int m = 0; m < 2; ++m) {
            const _Float16* qp = q + base + (long)(t0 + m * 64 + wid * 16 + r16) * HD + g * 8;
            qf[m][0] = *(const f16x8*)qp;
            qf[m][1] = *(const f16x8*)(qp + 32);
            #pragma unroll
            for (int u = 0; u < 8; ++u) {      // fold 1/sqrt(64)*log2(e): log2-domain scores
                qf[m][0][u] *= (_Float16)0.18033688f;
                qf[m][1][u] *= (_Float16)0.18033688f;
            }
        }
        float mrun[2] = {-INFINITY, -INFINITY};
        float lacc[2][4] = {{0.f, 0.f, 0.f, 0.f}, {0.f, 0.f, 0.f, 0.f}};
        f32x4 oacc[2][4];
        #pragma unroll
        for (int m = 0; m < 2; ++m)
            #pragma unroll
            for (int nb = 0; nb < 4; ++nb) oacc[m][nb] = (f32x4){0.f, 0.f, 0.f, 0.f};

        for (int jt = lo; jt < hi; ++jt) {
            __syncthreads();                   // all waves done with previous K/V tile
            STAGE(jt);
            __syncthreads();                   // vmcnt drained: Kd/Vd ready

            const bool skip0 = (jt == 2 * J + 1);      // m=0 fully masked on this step
            #pragma unroll
            for (int m = 0; m < 2; ++m) {
                if (m == 0 && skip0) continue;
                f32x4 s[4];
                __builtin_amdgcn_s_setprio(1);
                #pragma unroll
                for (int nb = 0; nb < 4; ++nb) {
                    int row = nb * 16 + r16;
                    f16x8 kb0 = *(const f16x8*)&Kd[row * 64 + (((g)     ^ (row & 7)) << 3)];
                    f16x8 kb1 = *(const f16x8*)&Kd[row * 64 + (((4 + g) ^ (row & 7)) << 3)];
                    f32x4 a0 = (f32x4){0.f, 0.f, 0.f, 0.f};
                    a0 = __builtin_amdgcn_mfma_f32_16x16x32_f16(qf[m][0], kb0, a0, 0, 0, 0);
                    a0 = __builtin_amdgcn_mfma_f32_16x16x32_f16(qf[m][1], kb1, a0, 0, 0, 0);
                    s[nb] = a0;
                }
                __builtin_amdgcn_s_setprio(0);
                if (jt == 2 * J + m) {         // diagonal tile for this m-pass
                    #pragma unroll
                    for (int nb = 0; nb < 4; ++nb)
                        #pragma unroll
                        for (int r = 0; r < 4; ++r)
                            if (nb * 16 + r16 > wid * 16 + g * 4 + r) s[nb][r] = -INFINITY;
                }
                SOFTPV(s, m)
            }
        }
        // epilogue: per-m row sums; l==0 rows (m-pass never ran) -> sentinel
        #pragma unroll
        for (int m = 0; m < 2; ++m) {
            float lsum[4], linv[4];
            #pragma unroll
            for (int r = 0; r < 4; ++r) {
                float Lr = lacc[m][r];
                #pragma unroll
                for (int off = 1; off < 16; off <<= 1) Lr += __shfl_xor(Lr, off);
                lsum[r] = Lr;
                linv[r] = (Lr > 0.f) ? 1.f / Lr : 0.f;
            }
            #pragma unroll
            for (int nb = 0; nb < 4; ++nb)
                #pragma unroll
                for (int r = 0; r < 4; ++r)
                    Op[(prow + m * 64 + wid * 16 + g * 4 + r) * HD + nb * 16 + r16] =
                        (_Float16)(oacc[m][nb][r] * linv[r]);
            if (r16 == 0)
                #pragma unroll
                for (int r = 0; r < 4; ++r)
                    ML[prow + m * 64 + wid * 16 + g * 4 + r] =
                        make_float2(lsum[r] > 0.f ? mrun[m] : -INFINITY, lsum[r]);
        }
    }
}

// ---------- combine NZ split partials -> y f16 (vectorized); block-reduced absmax ----------
__global__ __launch_bounds__(256)
void k_combine(const _Float16* __restrict__ Op, const float2* __restrict__ ML,
               _Float16* __restrict__ y, unsigned int* __restrict__ amax5) {
    __shared__ float wred[4];
    const int tid = threadIdx.x;
    const int c8 = (tid & 7) * 8;          // col start (8 f16)
    const int rsub = tid >> 3;             // 0..31
    float bmax = 0.f;
    #pragma unroll 1
    for (int it = 0; it < 8; ++it) {
        int row = blockIdx.x * 256 + it * 32 + rsub;     // 0..65535 = bh*2048 + t
        float2 ml[NZ];
        #pragma unroll
        for (int zz = 0; zz < NZ; ++zz) ml[zz] = ML[row + zz * 65536];
        float M = ml[0].x;
        #pragma unroll
        for (int zz = 1; zz < NZ; ++zz) M = fmaxf(M, ml[zz].x);
        float w[NZ]; float den = 0.f;
        #pragma unroll
        for (int zz = 0; zz < NZ; ++zz) { w[zz] = fexp2(ml[zz].x - M) * ml[zz].y; den += w[zz]; }
        float inv = 1.f / den;
        f16x8 o[NZ];
        #pragma unroll
        for (int zz = 0; zz < NZ; ++zz)
            o[zz] = *(const f16x8*)&Op[(long)(row + zz * 65536) * HD + c8];
        f16x8 res;
        #pragma unroll
        for (int u = 0; u < 8; ++u) {
            float num = 0.f;
            #pragma unroll
            for (int zz = 0; zz < NZ; ++zz) num += w[zz] * (float)o[zz][u];
            float val = num * inv;
            res[u] = (_Float16)val;
            bmax = fmaxf(bmax, fabsf(val));
        }
        int bh = row >> 11, t = row & 2047;
        *(f16x8*)&y[((long)((bh >> 4) * T_SEQ + t)) * D_MODEL + (bh & 15) * HD + c8] = res;
    }
    #pragma unroll
    for (int off = 1; off < 64; off <<= 1) bmax = fmaxf(bmax, __shfl_xor(bmax, off));
    if ((tid & 63) == 0) wred[tid >> 6] = bmax;
    __syncthreads();
    if (tid == 0) {
        float m = fmaxf(fmaxf(wred[0], wred[1]), fmaxf(wred[2], wred[3]));
        if (m > 0.f) atomicMax(amax5, __float_as_uint(m));
    }
}

// ---------------- launch ----------------
extern "C" void kernel_launch(void* const* d_in, const int* in_sizes, int n_in,
                              void* d_out, int out_size, void* d_ws, size_t ws_size,
                              hipStream_t stream) {
    const float* x  = (const float*)d_in[0];
    const float* Wq = (const float*)d_in[1];
    const float* bq = (const float*)d_in[2];
    const float* Wk = (const float*)d_in[3];
    const float* bk = (const float*)d_in[4];
    const float* Wv = (const float*)d_in[5];
    const float* bv = (const float*)d_in[6];
    const float* Wo = (const float*)d_in[7];
    const float* bo = (const float*)d_in[8];

    char* ws = (char*)d_ws;
    unsigned int* amax = (unsigned int*)ws;                     // slots at i*ASLOT (128 B apart)
    char* xq8 = ws + 4096;                                      // 4 MB
    char* wq8 = xq8 + 4194304L;                                 // 1 MB each
    char* wk8 = wq8 + 1048576L;
    char* wv8 = wk8 + 1048576L;
    char* wo8 = wv8 + 1048576L;
    char* p2 = ws + 4096 + 8388608L;
    _Float16* qh  = (_Float16*)p2;                              // 8 MB each
    _Float16* kh  = (_Float16*)(p2 + 8388608L);
    _Float16* vth = (_Float16*)(p2 + 16777216L);
    _Float16* ybh = (_Float16*)(p2 + 25165824L);                // 8 MB f16
    char*     yq8 = p2 + 33554432L;                             // 4 MB
    _Float16* Opart = (_Float16*)(p2 + 37748736L);              // 40 MB (5 slots)
    float2*   MLp   = (float2*)(p2 + 37748736L + 41943040L);    // 2.5 MB

    const long NY8 = (long)NB * T_SEQ * D_MODEL / 8;            // 524288

    (void)hipMemsetAsync(amax, 0, 1024, stream);
    k_absmax8<<<dim3(32, 8), 256, 0, stream>>>(x, Wq, Wk, Wv, Wo, amax);
    k_quant8<<<dim3(128, 8), 256, 0, stream>>>(x, Wq, Wk, Wv, Wo,
                                               xq8, wq8, wk8, wv8, wo8, amax);
    k_gemm_qkv<<<768, 256, 0, stream>>>(xq8, wq8, wk8, wv8, bq, bk, bv,
                                        amax, qh, kh, vth);
    k_attn<<<1280, 256, 0, stream>>>(qh, kh, vth, Opart, MLp);
    k_combine<<<256, 256, 0, stream>>>(Opart, MLp, ybh, amax + 5 * ASLOT);
    k_quant_h<<<512, 256, 0, stream>>>(ybh, yq8, amax + 5 * ASLOT, NY8);
    k_gemm_o<<<512, 256, 0, stream>>>(yq8, wo8, bo, amax + 5 * ASLOT, amax + 4 * ASLOT,
                                      (float*)d_out);
}

// Round 20
// 120.471 us; speedup vs baseline: 1.4885x; 1.0895x over previous
//
#include <hip/hip_runtime.h>
#include <hip/hip_fp16.h>

#define T_SEQ 2048
#define D_MODEL 1024
#define NB 2
#define NH 16
#define HD 64

using f16x8 = __attribute__((ext_vector_type(8))) _Float16;
using f16x4 = __attribute__((ext_vector_type(4))) _Float16;
using f32x4 = __attribute__((ext_vector_type(4))) float;
using i32x4 = __attribute__((ext_vector_type(4))) int;

// amax slots padded to 128 B (32 uints) apart: one cache line per slot
#define ASLOT 32

__device__ __forceinline__ float fexp2(float x) { return __builtin_amdgcn_exp2f(x); }

__device__ __forceinline__ void gload_lds16(const void* g, void* l) {
    __builtin_amdgcn_global_load_lds((const __attribute__((address_space(1))) void*)g,
                                     (__attribute__((address_space(3))) void*)l, 16, 0, 0);
}

// ---------- absmax: y<4 -> x slice y (slot 0); y>=4 -> W[y-4] (slot 1+y-4) ----------
__global__ __launch_bounds__(256)
void k_absmax8(const float* __restrict__ x,
               const float* __restrict__ w0, const float* __restrict__ w1,
               const float* __restrict__ w2, const float* __restrict__ w3,
               unsigned int* __restrict__ amax) {
    __shared__ float wred[4];
    const int y = blockIdx.y;
    const float* p; int slot;
    if (y < 4) { p = x + (long)y * 1048576; slot = 0; }
    else { int w = y - 4; p = (w == 0) ? w0 : (w == 1) ? w1 : (w == 2) ? w2 : w3; slot = 1 + w; }
    const float4* p4 = (const float4*)p;
    const long i0 = (long)blockIdx.x * 256 + threadIdx.x;   // 0..8191
    float m = 0.f;
    #pragma unroll 4
    for (int it = 0; it < 32; ++it) {                       // 32*8192 = 262144 float4
        float4 v = p4[i0 + (long)it * 8192];
        m = fmaxf(fmaxf(fmaxf(fabsf(v.x), fabsf(v.y)), fmaxf(fabsf(v.z), fabsf(v.w))), m);
    }
    #pragma unroll
    for (int off = 1; off < 64; off <<= 1) m = fmaxf(m, __shfl_xor(m, off));
    if ((threadIdx.x & 63) == 0) wred[threadIdx.x >> 6] = m;
    __syncthreads();
    if (threadIdx.x == 0) {
        float mm = fmaxf(fmaxf(wred[0], wred[1]), fmaxf(wred[2], wred[3]));
        if (mm > 0.f) atomicMax(amax + slot * ASLOT, __float_as_uint(mm));
    }
}

__device__ __forceinline__ unsigned int quant_pack4i(float4 v, float inv) {
    int q0 = (int)fminf(127.f, fmaxf(-128.f, rintf(v.x * inv)));
    int q1 = (int)fminf(127.f, fmaxf(-128.f, rintf(v.y * inv)));
    int q2 = (int)fminf(127.f, fmaxf(-128.f, rintf(v.z * inv)));
    int q3 = (int)fminf(127.f, fmaxf(-128.f, rintf(v.w * inv)));
    return (q0 & 255) | ((q1 & 255) << 8) | ((q2 & 255) << 16) | ((q3 & 255) << 24);
}

// ---------- quantize to int8 codes: same y decode as k_absmax8 ----------
__global__ __launch_bounds__(256)
void k_quant8(const float* __restrict__ x,
              const float* __restrict__ w0, const float* __restrict__ w1,
              const float* __restrict__ w2, const float* __restrict__ w3,
              char* __restrict__ xq,
              char* __restrict__ o0, char* __restrict__ o1,
              char* __restrict__ o2, char* __restrict__ o3,
              const unsigned int* __restrict__ amax) {
    const int y = blockIdx.y;
    const float* p; char* o; int slot;
    if (y < 4) { p = x + (long)y * 1048576; o = xq + (long)y * 1048576; slot = 0; }
    else {
        int w = y - 4;
        p = (w == 0) ? w0 : (w == 1) ? w1 : (w == 2) ? w2 : w3;
        o = (w == 0) ? o0 : (w == 1) ? o1 : (w == 2) ? o2 : o3;
        slot = 1 + w;
    }
    float scale = fmaxf(__uint_as_float(amax[slot * ASLOT]) / 127.0f, 1e-8f);
    float inv = 1.0f / scale;
    const long n4 = 262144;
    long i = (long)blockIdx.x * blockDim.x + threadIdx.x;
    const long stride = (long)gridDim.x * blockDim.x;
    for (; i < n4; i += stride)
        ((unsigned int*)o)[i] = quant_pack4i(((const float4*)p)[i], inv);
}

// ---------- quantize f16 y -> int8 codes ----------
__global__ __launch_bounds__(256)
void k_quant_h(const _Float16* __restrict__ in, char* __restrict__ out,
               const unsigned int* __restrict__ amax, long n8) {
    float scale = fmaxf(__uint_as_float(*amax) / 127.0f, 1e-8f);
    float inv = 1.0f / scale;
    long i = (long)blockIdx.x * blockDim.x + threadIdx.x;
    const long stride = (long)gridDim.x * blockDim.x;
    for (; i < n8; i += stride) {
        f16x8 v = ((const f16x8*)in)[i];
        unsigned int lo = 0, hi = 0;
        #pragma unroll
        for (int u = 0; u < 4; ++u) {
            int q = (int)fminf(127.f, fmaxf(-128.f, rintf((float)v[u] * inv)));
            lo |= (unsigned int)(q & 255) << (8 * u);
        }
        #pragma unroll
        for (int u = 0; u < 4; ++u) {
            int q = (int)fminf(127.f, fmaxf(-128.f, rintf((float)v[4 + u] * inv)));
            hi |= (unsigned int)(q & 255) << (8 * u);
        }
        ((uint2*)out)[i] = make_uint2(lo, hi);
    }
}

// ---------- shared i8 GEMM core: 128x128 tile, BK=128, chunk-XOR swizzled LDS ----------
__device__ __forceinline__ void gemm_core8(const char* __restrict__ A,
                                           const char* __restrict__ Bw,
                                           int m0, int n0, int tid, i32x4 (&acc)[4][4]) {
    __shared__ char Asm[128 * 128];
    __shared__ char Bsm[128 * 128];
    const int lane = tid & 63, wid = tid >> 6;
    const int r16 = lane & 15, g = lane >> 4;
    const int wr = wid >> 1, wc = wid & 1;
    #pragma unroll
    for (int m = 0; m < 4; ++m)
        #pragma unroll
        for (int n = 0; n < 4; ++n) acc[m][n] = (i32x4){0, 0, 0, 0};
    for (int kt = 0; kt < 1024; kt += 128) {
        __syncthreads();
        #pragma unroll
        for (int s2 = 0; s2 < 4; ++s2) {
            int c = tid + s2 * 256;              // 0..1023 chunks of 16B per matrix
            int row = c >> 3, ch = c & 7;
            int chs = ch ^ (row & 7);            // pre-swizzled global source chunk
            gload_lds16(&A[(long)(m0 + row) * 1024 + kt + chs * 16], &Asm[c * 16]);
            gload_lds16(&Bw[(long)(n0 + row) * 1024 + kt + chs * 16], &Bsm[c * 16]);
        }
        __syncthreads();
        #pragma unroll
        for (int kk = 0; kk < 2; ++kk) {
            i32x4 af[4], bf[4];
            #pragma unroll
            for (int m = 0; m < 4; ++m) {
                int row = wr * 64 + m * 16 + r16;
                af[m] = *(const i32x4*)&Asm[row * 128 + (((kk * 4 + g) ^ (row & 7)) << 4)];
            }
            #pragma unroll
            for (int n = 0; n < 4; ++n) {
                int row = wc * 64 + n * 16 + r16;
                bf[n] = *(const i32x4*)&Bsm[row * 128 + (((kk * 4 + g) ^ (row & 7)) << 4)];
            }
            #pragma unroll
            for (int m = 0; m < 4; ++m)
                #pragma unroll
                for (int n = 0; n < 4; ++n)
                    acc[m][n] = __builtin_amdgcn_mfma_i32_16x16x64_i8(af[m], bf[n], acc[m][n], 0, 0, 0);
        }
    }
}

// ---------- fused QKV projection, XCD-swizzled 1D grid (768 blocks) ----------
// decode: xcd=L&7, t=L>>3; my=xcd*4+(t&3), nx=(t>>2)&7, z=t>>5  -> per-XCD: 4 A-panels + 1 W
__global__ __launch_bounds__(256)
void k_gemm_qkv(const char* __restrict__ A,
                const char* __restrict__ wq, const char* __restrict__ wk,
                const char* __restrict__ wv,
                const float* __restrict__ bq, const float* __restrict__ bk,
                const float* __restrict__ bv,
                const unsigned int* __restrict__ amax,
                _Float16* __restrict__ qo, _Float16* __restrict__ ko,
                _Float16* __restrict__ vto) {
    const int L = blockIdx.x;
    const int t = L >> 3;
    const int my = (L & 7) * 4 + (t & 3);
    const int nx = (t >> 2) & 7;
    const int z = t >> 5;
    const char* Bw = (z == 0) ? wq : (z == 1) ? wk : wv;
    const float* bias = (z == 0) ? bq : (z == 1) ? bk : bv;
    const int tid = threadIdx.x;
    const int m0 = my * 128, n0 = nx * 128;
    const int lane = tid & 63, wid = tid >> 6;
    const int r16 = lane & 15, g = lane >> 4;
    const int wr = wid >> 1, wc = wid & 1;

    i32x4 acc[4][4];
    gemm_core8(A, Bw, m0, n0, tid, acc);

    float sA = fmaxf(__uint_as_float(amax[0]) / 127.0f, 1e-8f);
    float sB = fmaxf(__uint_as_float(amax[(1 + z) * ASLOT]) / 127.0f, 1e-8f);
    float s = sA * sB;
    if (z < 2) {
        _Float16* out = (z == 0) ? qo : ko;
        #pragma unroll
        for (int m = 0; m < 4; ++m)
            #pragma unroll
            for (int n = 0; n < 4; ++n) {
                int col = n0 + wc * 64 + n * 16 + r16;
                float bcol = bias[col];
                int h = col >> 6, d = col & 63;
                #pragma unroll
                for (int r = 0; r < 4; ++r) {
                    int row = m0 + wr * 64 + m * 16 + g * 4 + r;
                    int b = row >> 11, tt = row & 2047;
                    out[(((long)(b * NH + h)) * T_SEQ + tt) * HD + d] =
                        (_Float16)((float)acc[m][n][r] * s + bcol);
                }
            }
    } else {
        #pragma unroll
        for (int m = 0; m < 4; ++m)
            #pragma unroll
            for (int n = 0; n < 4; ++n) {
                int col = n0 + wc * 64 + n * 16 + r16;
                float bcol = bias[col];
                int h = col >> 6, d = col & 63;
                int row0 = m0 + wr * 64 + m * 16 + g * 4;
                int b = row0 >> 11, tt = row0 & 2047;
                f16x4 pk;
                #pragma unroll
                for (int r = 0; r < 4; ++r) pk[r] = (_Float16)((float)acc[m][n][r] * s + bcol);
                *(f16x4*)&vto[(((long)(b * NH + h)) * HD + d) * T_SEQ + tt] = pk;
            }
    }
}

// ---------- output projection GEMM, i8, 128x64 tiles, BK=128, XCD-swizzled (512) ----------
__global__ __launch_bounds__(256)
void k_gemm_o(const char* __restrict__ A, const char* __restrict__ Bw,
              const float* __restrict__ bias,
              const unsigned int* __restrict__ amaxA, const unsigned int* __restrict__ amaxB,
              float* __restrict__ out) {
    __shared__ char Asm[128 * 128];
    __shared__ char Bsm[64 * 128];
    const int L = blockIdx.x;
    const int t = L >> 3;
    const int my = (L & 7) * 4 + (t & 3);
    const int nx = t >> 2;                 // 0..15
    const int tid = threadIdx.x;
    const int m0 = my * 128, n0 = nx * 64;
    const int lane = tid & 63, wid = tid >> 6;
    const int r16 = lane & 15, g = lane >> 4;
    const int wr = wid >> 1, wc = wid & 1;

    i32x4 acc[4][2];
    #pragma unroll
    for (int m = 0; m < 4; ++m)
        #pragma unroll
        for (int n = 0; n < 2; ++n) acc[m][n] = (i32x4){0, 0, 0, 0};

    for (int kt = 0; kt < 1024; kt += 128) {
        __syncthreads();
        #pragma unroll
        for (int s2 = 0; s2 < 4; ++s2) {
            int c = tid + s2 * 256;              // A: 1024 chunks
            int row = c >> 3, ch = c & 7;
            int chs = ch ^ (row & 7);
            gload_lds16(&A[(long)(m0 + row) * 1024 + kt + chs * 16], &Asm[c * 16]);
        }
        #pragma unroll
        for (int s2 = 0; s2 < 2; ++s2) {
            int c = tid + s2 * 256;              // B: 512 chunks
            int row = c >> 3, ch = c & 7;
            int chs = ch ^ (row & 7);
            gload_lds16(&Bw[(long)(n0 + row) * 1024 + kt + chs * 16], &Bsm[c * 16]);
        }
        __syncthreads();
        #pragma unroll
        for (int kk = 0; kk < 2; ++kk) {
            i32x4 af[4], bf[2];
            #pragma unroll
            for (int m = 0; m < 4; ++m) {
                int row = wr * 64 + m * 16 + r16;
                af[m] = *(const i32x4*)&Asm[row * 128 + (((kk * 4 + g) ^ (row & 7)) << 4)];
            }
            #pragma unroll
            for (int n = 0; n < 2; ++n) {
                int row = wc * 32 + n * 16 + r16;
                bf[n] = *(const i32x4*)&Bsm[row * 128 + (((kk * 4 + g) ^ (row & 7)) << 4)];
            }
            #pragma unroll
            for (int m = 0; m < 4; ++m)
                #pragma unroll
                for (int n = 0; n < 2; ++n)
                    acc[m][n] = __builtin_amdgcn_mfma_i32_16x16x64_i8(af[m], bf[n], acc[m][n], 0, 0, 0);
        }
    }

    float sA = fmaxf(__uint_as_float(*amaxA) / 127.0f, 1e-8f);
    float sB = fmaxf(__uint_as_float(*amaxB) / 127.0f, 1e-8f);
    float s = sA * sB;
    #pragma unroll
    for (int m = 0; m < 4; ++m)
        #pragma unroll
        for (int n = 0; n < 2; ++n) {
            int col = n0 + wc * 32 + n * 16 + r16;
            float bcol = bias[col];
            #pragma unroll
            for (int r = 0; r < 4; ++r) {
                int row = m0 + wr * 64 + m * 16 + g * 4 + r;
                out[(long)row * 1024 + col] = (float)acc[m][n][r] * s + bcol;
            }
        }
}

// softmax + P-write + PV for one m-pass (R11 proven version); MI is a literal.
#define SOFTPV(S, MI)                                                                   \
    {                                                                                   \
        float t0_ = fmaxf(fmaxf(S[0][0], S[0][1]), fmaxf(S[0][2], S[0][3]));            \
        float t1_ = fmaxf(fmaxf(S[1][0], S[1][1]), fmaxf(S[1][2], S[1][3]));            \
        float t2_ = fmaxf(fmaxf(S[2][0], S[2][1]), fmaxf(S[2][2], S[2][3]));            \
        float t3_ = fmaxf(fmaxf(S[3][0], S[3][1]), fmaxf(S[3][2], S[3][3]));            \
        float Ml = fmaxf(fmaxf(t0_, t1_), fmaxf(t2_, t3_));                             \
        if (__any(Ml > mrun[MI] + 11.5f)) {                                             \
            float M = Ml;                                                               \
            _Pragma("unroll")                                                           \
            for (int off = 1; off < 64; off <<= 1) M = fmaxf(M, __shfl_xor(M, off));    \
            float corr = fexp2(mrun[MI] - M);                                           \
            _Pragma("unroll")                                                           \
            for (int r = 0; r < 4; ++r) lacc[MI][r] *= corr;                            \
            _Pragma("unroll")                                                           \
            for (int nb = 0; nb < 4; ++nb)                                              \
                _Pragma("unroll")                                                       \
                for (int r = 0; r < 4; ++r) oacc[MI][nb][r] *= corr;                    \
            mrun[MI] = M;                                                               \
        }                                                                               \
        _Pragma("unroll")                                                               \
        for (int nb = 0; nb < 4; ++nb)                                                  \
            _Pragma("unroll")                                                           \
            for (int r = 0; r < 4; ++r) {                                               \
                float pv = fexp2(S[nb][r] - mrun[MI]);                                  \
                lacc[MI][r] += pv;                                                      \
                int row = g * 4 + r, col = nb * 16 + r16;                               \
                int c8 = col >> 3;                                                      \
                Psm[wid][row * 64 + ((c8 ^ (row & 7)) << 3) + (col & 7)] = (_Float16)pv;\
            }                                                                           \
        f16x8 pa0 = *(const f16x8*)&Psm[wid][r16 * 64 + (((g)     ^ (r16 & 7)) << 3)];  \
        f16x8 pa1 = *(const f16x8*)&Psm[wid][r16 * 64 + (((4 + g) ^ (r16 & 7)) << 3)];  \
        __builtin_amdgcn_s_setprio(1);                                                  \
        _Pragma("unroll")                                                               \
        for (int nb = 0; nb < 4; ++nb) {                                                \
            int row = nb * 16 + r16;                                                    \
            f16x8 vb0 = *(const f16x8*)&Vd[row * 64 + (((g)     ^ (row & 7)) << 3)];    \
            f16x8 vb1 = *(const f16x8*)&Vd[row * 64 + (((4 + g) ^ (row & 7)) << 3)];    \
            oacc[MI][nb] = __builtin_amdgcn_mfma_f32_16x16x32_f16(pa0, vb0, oacc[MI][nb], 0, 0, 0); \
            oacc[MI][nb] = __builtin_amdgcn_mfma_f32_16x16x32_f16(pa1, vb1, oacc[MI][nb], 0, 0, 0); \
        }                                                                               \
        __builtin_amdgcn_s_setprio(0);                                                  \
    }

// ---------- flash attention: single-buffer K/V (LDS 24576), 4-way split, 1024 blocks ----------
// QBLK=128 time-multiplexed m-passes, pair (Jh=15-p, Jl=p), XCD bh grouping.
// L decode: bh=(L&7)*4+((L>>3)&3); rest=L>>5: p=rest>>2 (0..7), z=rest&3.
// Slices [0,8,17,25,34). Two barriers per K-step.
__global__ __launch_bounds__(256)
void k_attn(const _Float16* __restrict__ q, const _Float16* __restrict__ kk,
            const _Float16* __restrict__ vt,
            _Float16* __restrict__ Op, float2* __restrict__ ML) {
    __shared__ _Float16 Kd[4096];          // [64][64] linear, chunk-XOR swizzled
    __shared__ _Float16 Vd[4096];
    __shared__ _Float16 Psm[4][1024];      // [16][64] per wave, time-shared across m

    const int L = blockIdx.x;
    const int bh = (L & 7) * 4 + ((L >> 3) & 3);
    const int rest = L >> 5;               // 0..31
    const int p = rest >> 2, z = rest & 3;
    const int tid = threadIdx.x, wid = tid >> 6, lane = tid & 63;
    const int r16 = lane & 15, g = lane >> 4;
    const long base = (long)bh * T_SEQ * HD;
    const long vbase = (long)bh * HD * T_SEQ;
    const int nkh = 2 * (15 - p) + 2;      // K-steps in Jh sub (Jh = 15-p)
    const int a = (34 * z) >> 2, b2 = (34 * (z + 1)) >> 2;   // 0,8,17,25,34

    auto STAGE = [&](int jt) {
        const _Float16* kp = kk + base + (long)jt * 64 * HD;
        const _Float16* vp = vt + vbase + jt * 64;
        #pragma unroll
        for (int s2 = 0; s2 < 2; ++s2) {
            int slot = tid + s2 * 256;           // linear LDS chunk (dest = base + lane*16)
            int row = slot >> 3;
            int ch = (slot & 7) ^ (row & 7);     // pre-swizzled global source chunk
            gload_lds16(kp + row * HD + ch * 8, &Kd[slot * 8]);
            gload_lds16(vp + (long)row * T_SEQ + ch * 8, &Vd[slot * 8]);
        }
    };

    #pragma unroll 1
    for (int sub = 0; sub < 2; ++sub) {
        const int J = sub ? p : (15 - p);
        const int nk = 2 * J + 2;
        const int lo = sub ? max(a - nkh, 0) : a;
        const int hi = sub ? max(b2 - nkh, 0) : min(b2, nk);
        const int t0 = J * 128;
        const long prow = (long)(z * 32 + bh) * T_SEQ + t0;

        if (lo >= hi) {                        // slice doesn't touch this Q-tile: sentinels
            f16x8 zz = {};
            #pragma unroll 1
            for (int i = tid; i < 1024; i += 256) {      // 128 rows x 8 chunks
                int row = i >> 3, ch = i & 7;
                *(f16x8*)&Op[(prow + row) * HD + ch * 8] = zz;
            }
            if (tid < 128) ML[prow + tid] = make_float2(-INFINITY, 0.f);
            continue;
        }

        f16x8 qf[2][2];
        #pragma unroll
        for (int m = 0; m < 2; ++m) {
            const _Float16* qp = q + base + (long)(t0 + m * 64 + wid * 16 + r16) * HD + g * 8;
            qf[m][0] = *(const f16x8*)qp;
            qf[m][1] = *(const f16x8*)(qp + 32);
            #pragma unroll
            for (int u = 0; u < 8; ++u) {      // fold 1/sqrt(64)*log2(e): log2-domain scores
                qf[m][0][u] *= (_Float16)0.18033688f;
                qf[m][1][u] *= (_Float16)0.18033688f;
            }
        }
        float mrun[2] = {-INFINITY, -INFINITY};
        float lacc[2][4] = {{0.f, 0.f, 0.f, 0.f}, {0.f, 0.f, 0.f, 0.f}};
        f32x4 oacc[2][4];
        #pragma unroll
        for (int m = 0; m < 2; ++m)
            #pragma unroll
            for (int nb = 0; nb < 4; ++nb) oacc[m][nb] = (f32x4){0.f, 0.f, 0.f, 0.f};

        for (int jt = lo; jt < hi; ++jt) {
            __syncthreads();                   // all waves done with previous K/V tile
            STAGE(jt);
            __syncthreads();                   // vmcnt drained: Kd/Vd ready

            const bool skip0 = (jt == 2 * J + 1);      // m=0 fully masked on this step
            #pragma unroll
            for (int m = 0; m < 2; ++m) {
                if (m == 0 && skip0) continue;
                f32x4 s[4];
                __builtin_amdgcn_s_setprio(1);
                #pragma unroll
                for (int nb = 0; nb < 4; ++nb) {
                    int row = nb * 16 + r16;
                    f16x8 kb0 = *(const f16x8*)&Kd[row * 64 + (((g)     ^ (row & 7)) << 3)];
                    f16x8 kb1 = *(const f16x8*)&Kd[row * 64 + (((4 + g) ^ (row & 7)) << 3)];
                    f32x4 a0 = (f32x4){0.f, 0.f, 0.f, 0.f};
                    a0 = __builtin_amdgcn_mfma_f32_16x16x32_f16(qf[m][0], kb0, a0, 0, 0, 0);
                    a0 = __builtin_amdgcn_mfma_f32_16x16x32_f16(qf[m][1], kb1, a0, 0, 0, 0);
                    s[nb] = a0;
                }
                __builtin_amdgcn_s_setprio(0);
                if (jt == 2 * J + m) {         // diagonal tile for this m-pass
                    #pragma unroll
                    for (int nb = 0; nb < 4; ++nb)
                        #pragma unroll
                        for (int r = 0; r < 4; ++r)
                            if (nb * 16 + r16 > wid * 16 + g * 4 + r) s[nb][r] = -INFINITY;
                }
                SOFTPV(s, m)
            }
        }
        // epilogue: per-m row sums; l==0 rows (m-pass never ran) -> sentinel
        #pragma unroll
        for (int m = 0; m < 2; ++m) {
            float lsum[4], linv[4];
            #pragma unroll
            for (int r = 0; r < 4; ++r) {
                float Lr = lacc[m][r];
                #pragma unroll
                for (int off = 1; off < 16; off <<= 1) Lr += __shfl_xor(Lr, off);
                lsum[r] = Lr;
                linv[r] = (Lr > 0.f) ? 1.f / Lr : 0.f;
            }
            #pragma unroll
            for (int nb = 0; nb < 4; ++nb)
                #pragma unroll
                for (int r = 0; r < 4; ++r)
                    Op[(prow + m * 64 + wid * 16 + g * 4 + r) * HD + nb * 16 + r16] =
                        (_Float16)(oacc[m][nb][r] * linv[r]);
            if (r16 == 0)
                #pragma unroll
                for (int r = 0; r < 4; ++r)
                    ML[prow + m * 64 + wid * 16 + g * 4 + r] =
                        make_float2(lsum[r] > 0.f ? mrun[m] : -INFINITY, lsum[r]);
        }
    }
}

// ---------- combine 4 split partials -> y f16 (vectorized); block-reduced absmax ----------
__global__ __launch_bounds__(256)
void k_combine(const _Float16* __restrict__ Op, const float2* __restrict__ ML,
               _Float16* __restrict__ y, unsigned int* __restrict__ amax5) {
    __shared__ float wred[4];
    const int tid = threadIdx.x;
    const int c8 = (tid & 7) * 8;          // col start (8 f16)
    const int rsub = tid >> 3;             // 0..31
    float bmax = 0.f;
    #pragma unroll 1
    for (int it = 0; it < 8; ++it) {
        int row = blockIdx.x * 256 + it * 32 + rsub;     // 0..65535 = bh*2048 + t
        float2 ml[4];
        #pragma unroll
        for (int zz = 0; zz < 4; ++zz) ml[zz] = ML[row + zz * 65536];
        float M = fmaxf(fmaxf(ml[0].x, ml[1].x), fmaxf(ml[2].x, ml[3].x));
        float w[4]; float den = 0.f;
        #pragma unroll
        for (int zz = 0; zz < 4; ++zz) { w[zz] = fexp2(ml[zz].x - M) * ml[zz].y; den += w[zz]; }
        float inv = 1.f / den;
        f16x8 o[4];
        #pragma unroll
        for (int zz = 0; zz < 4; ++zz)
            o[zz] = *(const f16x8*)&Op[(long)(row + zz * 65536) * HD + c8];
        f16x8 res;
        #pragma unroll
        for (int u = 0; u < 8; ++u) {
            float num = w[0] * (float)o[0][u] + w[1] * (float)o[1][u]
                      + w[2] * (float)o[2][u] + w[3] * (float)o[3][u];
            float val = num * inv;
            res[u] = (_Float16)val;
            bmax = fmaxf(bmax, fabsf(val));
        }
        int bh = row >> 11, t = row & 2047;
        *(f16x8*)&y[((long)((bh >> 4) * T_SEQ + t)) * D_MODEL + (bh & 15) * HD + c8] = res;
    }
    #pragma unroll
    for (int off = 1; off < 64; off <<= 1) bmax = fmaxf(bmax, __shfl_xor(bmax, off));
    if ((tid & 63) == 0) wred[tid >> 6] = bmax;
    __syncthreads();
    if (tid == 0) {
        float m = fmaxf(fmaxf(wred[0], wred[1]), fmaxf(wred[2], wred[3]));
        if (m > 0.f) atomicMax(amax5, __float_as_uint(m));
    }
}

// ---------------- launch ----------------
extern "C" void kernel_launch(void* const* d_in, const int* in_sizes, int n_in,
                              void* d_out, int out_size, void* d_ws, size_t ws_size,
                              hipStream_t stream) {
    const float* x  = (const float*)d_in[0];
    const float* Wq = (const float*)d_in[1];
    const float* bq = (const float*)d_in[2];
    const float* Wk = (const float*)d_in[3];
    const float* bk = (const float*)d_in[4];
    const float* Wv = (const float*)d_in[5];
    const float* bv = (const float*)d_in[6];
    const float* Wo = (const float*)d_in[7];
    const float* bo = (const float*)d_in[8];

    char* ws = (char*)d_ws;
    unsigned int* amax = (unsigned int*)ws;                     // slots at i*ASLOT (128 B apart)
    char* xq8 = ws + 4096;                                      // 4 MB
    char* wq8 = xq8 + 4194304L;                                 // 1 MB each
    char* wk8 = wq8 + 1048576L;
    char* wv8 = wk8 + 1048576L;
    char* wo8 = wv8 + 1048576L;
    char* p2 = ws + 4096 + 8388608L;
    _Float16* qh  = (_Float16*)p2;                              // 8 MB each
    _Float16* kh  = (_Float16*)(p2 + 8388608L);
    _Float16* vth = (_Float16*)(p2 + 16777216L);
    _Float16* ybh = (_Float16*)(p2 + 25165824L);                // 8 MB f16
    char*     yq8 = p2 + 33554432L;                             // 4 MB
    _Float16* Opart = (_Float16*)(p2 + 37748736L);              // 32 MB (4 slots)
    float2*   MLp   = (float2*)(p2 + 71303168L);                // 2 MB

    const long NY8 = (long)NB * T_SEQ * D_MODEL / 8;            // 524288

    (void)hipMemsetAsync(amax, 0, 1024, stream);
    k_absmax8<<<dim3(32, 8), 256, 0, stream>>>(x, Wq, Wk, Wv, Wo, amax);
    k_quant8<<<dim3(128, 8), 256, 0, stream>>>(x, Wq, Wk, Wv, Wo,
                                               xq8, wq8, wk8, wv8, wo8, amax);
    k_gemm_qkv<<<768, 256, 0, stream>>>(xq8, wq8, wk8, wv8, bq, bk, bv,
                                        amax, qh, kh, vth);
    k_attn<<<1024, 256, 0, stream>>>(qh, kh, vth, Opart, MLp);
    k_combine<<<256, 256, 0, stream>>>(Opart, MLp, ybh, amax + 5 * ASLOT);
    k_quant_h<<<512, 256, 0, stream>>>(ybh, yq8, amax + 5 * ASLOT, NY8);
    k_gemm_o<<<512, 256, 0, stream>>>(yq8, wo8, bo, amax + 5 * ASLOT, amax + 4 * ASLOT,
                                      (float*)d_out);
}